// Round 9
// baseline (182.619 us; speedup 1.0000x reference)
//
#include <hip/hip_runtime.h>
#include <math.h>

#define BB 256
#define II 2048
#define CC 10
#define DOUT 16
#define COW 160                 // C*DOUT
#define WELEMS (II*CC*DOUT*8)   // 2,621,440 W elements

typedef short  short8v __attribute__((ext_vector_type(8)));
typedef float  f32x4   __attribute__((ext_vector_type(4)));

__device__ __forceinline__ ushort f2bf(float x) {   // RNE f32 -> bf16 bits
    union { float f; unsigned u; } v; v.f = x;
    unsigned r = v.u + 0x7fff + ((v.u >> 16) & 1);
    return (ushort)(r >> 16);
}
__device__ __forceinline__ float bf2f(ushort h) {
    union { unsigned u; float f; } v; v.u = ((unsigned)h) << 16; return v.f;
}
__device__ __forceinline__ short8v pack8(float a0, float a1, float a2, float a3,
                                         float b0, float b1, float b2, float b3) {
    short8v r;
    r[0]=(short)f2bf(a0); r[1]=(short)f2bf(a1); r[2]=(short)f2bf(a2); r[3]=(short)f2bf(a3);
    r[4]=(short)f2bf(b0); r[5]=(short)f2bf(b1); r[6]=(short)f2bf(b2); r[7]=(short)f2bf(b3);
    return r;
}

// ---------------- W f32 -> bf16, once ----------------
__global__ __launch_bounds__(256)
void wcvt(const float* __restrict__ W, ushort* __restrict__ Wb)
{
    const size_t e = ((size_t)blockIdx.x * 256 + threadIdx.x) * 8;
    const float4 x0 = *(const float4*)(W + e);
    const float4 x1 = *(const float4*)(W + e + 4);
    *(short8v*)(Wb + e) = pack8(x0.x, x0.y, x0.z, x0.w, x1.x, x1.y, x1.z, x1.w);
}

// ---------------- MODE 0 via MFMA ----------------
template<int LEN>
__global__ __launch_bounds__(256, 4)
void caps_pass0_mfma(const float* __restrict__ u, const ushort* __restrict__ Wb,
                     float* __restrict__ p)
{
    __shared__ ushort u_lds[64 * LEN * 8];

    const int tid  = threadIdx.x;
    const int l    = tid & 63;
    const int quad = tid >> 6;
    const int bbase = blockIdx.y * 64;
    const int i0    = blockIdx.x * LEN;

    const int ROWF = LEN * 8;
    for (int e = tid * 4; e < 64 * ROWF; e += 1024) {
        const int rb = e / ROWF, er = e % ROWF;
        const int i = er >> 3, dh = er & 7;
        const float4 x = *(const float4*)(u + ((size_t)(bbase + rb) * II + i0 + i) * 8 + dh);
        ushort4 h;
        h.x = f2bf(x.x); h.y = f2bf(x.y); h.z = f2bf(x.z); h.w = f2bf(x.w);
        *(ushort4*)&u_lds[rb * ROWF + (i ^ (rb & 7)) * 8 + dh] = h;
    }
    __syncthreads();

    f32x4 acc[CC];
#pragma unroll
    for (int c = 0; c < CC; ++c) acc[c] = (f32x4){0.f, 0.f, 0.f, 0.f};

    const int arow = quad * 16 + (l & 15);
#pragma unroll
    for (int g = 0; g < LEN / 4; ++g) {
        const int ia = g * 4 + (l >> 4);
        const short8v af = *(const short8v*)&u_lds[arow * ROWF + ((ia ^ (arow & 7)) * 8)];
        const short8v* wg = (const short8v*)(Wb + (size_t)(i0 + ia) * (CC*128) + (l & 15) * 8);
#pragma unroll
        for (int c = 0; c < CC; ++c)
            acc[c] = __builtin_amdgcn_mfma_f32_16x16x32_bf16(af, wg[c * 16], acc[c], 0, 0, 0);
    }

    float* pp = p + (size_t)blockIdx.x * (BB * COW);
#pragma unroll
    for (int c = 0; c < CC; ++c)
#pragma unroll
        for (int r = 0; r < 4; ++r) {
            const int b = bbase + quad * 16 + (l >> 4) * 4 + r;
            pp[b * COW + c * DOUT + (l & 15)] = acc[c][r] * 0.1f;
        }
}

// ---------------- MODES 1/2: 8 waves, barrier-free, all-register softmax ------
// wave = (wq = b-quadrant, ih = iq parity); each wave runs LEN/8 iq's.
// Per iq: uh^T via 4 masked MFMAs; agreement dot4 + xor16 + xor32 leaves
// a[b=o4, j] in EVERY lane; keep j==g (3 cndmasks) -> tk[c] in regs;
// softmax in regs; fold MFMA with B = cij*u. p row = blockIdx.x*2 + ih.
template<int MODE, int LEN>
__global__ __launch_bounds__(512, 4)
void caps_route(const float* __restrict__ u, const ushort* __restrict__ Wb,
                const float* __restrict__ v0, const float* __restrict__ v1,
                float* __restrict__ p)
{
    constexpr int RF = LEN * 8;
    __shared__ ushort u_lds[64 * RF];

    const int tid = threadIdx.x;
    const int l   = tid & 63;
    const int w   = tid >> 6;        // 0..7
    const int wq  = w & 3;           // b-quadrant
    const int ih  = w >> 2;          // iq parity
    const int o4  = l & 15;
    const int g   = l >> 4;
    const int bbase = blockIdx.y * 64;
    const int i0    = blockIdx.x * LEN;

    // ---- stage u -> bf16 LDS (cooperative, coalesced) ----
    for (int e = tid * 4; e < 64 * RF; e += 2048) {
        const int rb = e / RF, er = e % RF;
        const int i = er >> 3, dh = er & 7;
        const float4 x = *(const float4*)(u + ((size_t)(bbase + rb) * II + i0 + i) * 8 + dh);
        ushort4 h;
        h.x = f2bf(x.x); h.y = f2bf(x.y); h.z = f2bf(x.z); h.w = f2bf(x.w);
        *(ushort4*)&u_lds[rb * RF + (i ^ (rb & 7)) * 8 + dh] = h;
    }

    const int brow  = wq * 16 + o4;
    const int b_abs = bbase + brow;

    // ---- v (or v0+v1) packed bf16: vb[c][q] = lo:v[4g+2q], hi:v[4g+2q+1] ----
    unsigned vb[CC][2];
#pragma unroll
    for (int c = 0; c < CC; ++c) {
        float4 x = *(const float4*)(v0 + b_abs * COW + c * DOUT + 4 * g);
        if constexpr (MODE == 2) {
            const float4 y = *(const float4*)(v1 + b_abs * COW + c * DOUT + 4 * g);
            x.x += y.x; x.y += y.y; x.z += y.z; x.w += y.w;
        }
        vb[c][0] = (unsigned)f2bf(x.x) | ((unsigned)f2bf(x.y) << 16);
        vb[c][1] = (unsigned)f2bf(x.z) | ((unsigned)f2bf(x.w) << 16);
    }

    f32x4 acc[CC];
#pragma unroll
    for (int c = 0; c < CC; ++c) acc[c] = (f32x4){0.f, 0.f, 0.f, 0.f};
    const short8v zero8 = {0,0,0,0,0,0,0,0};
    const f32x4   zacc  = (f32x4){0.f, 0.f, 0.f, 0.f};

    __syncthreads();   // the ONLY barrier

    for (int t = 0; t < LEN / 8; ++t) {
        const int iq  = ih + 2 * t;
        const int il4 = iq * 4;
        const short8v u8 = *(const short8v*)
            &u_lds[brow * RF + (((il4 + g) ^ (brow & 7)) * 8)];
        float uf[8];
#pragma unroll
        for (int e = 0; e < 8; ++e) uf[e] = bf2f((ushort)u8[e]);

        float tk[CC];
        // ---- agreement ----
#pragma unroll
        for (int c = 0; c < CC; ++c) {
            const short8v w8 = *(const short8v*)
                &Wb[((size_t)(i0 + il4 + g) * CC + c) * 128 + o4 * 8];
            f32x4 uh[4];
#pragma unroll
            for (int j = 0; j < 4; ++j)
                uh[j] = __builtin_amdgcn_mfma_f32_16x16x32_bf16(
                    w8, (g == j) ? u8 : zero8, zacc, 0, 0, 0);
            const float vl0 = __uint_as_float(vb[c][0] << 16);
            const float vh0 = __uint_as_float(vb[c][0] & 0xFFFF0000u);
            const float vl1 = __uint_as_float(vb[c][1] << 16);
            const float vh1 = __uint_as_float(vb[c][1] & 0xFFFF0000u);
            float d0 = uh[0][0]*vl0 + uh[0][1]*vh0 + uh[0][2]*vl1 + uh[0][3]*vh1;
            float d1 = uh[1][0]*vl0 + uh[1][1]*vh0 + uh[1][2]*vl1 + uh[1][3]*vh1;
            float d2 = uh[2][0]*vl0 + uh[2][1]*vh0 + uh[2][2]*vl1 + uh[2][3]*vh1;
            float d3 = uh[3][0]*vl0 + uh[3][1]*vh0 + uh[3][2]*vl1 + uh[3][3]*vh1;
            d0 += __shfl_xor(d0, 16); d0 += __shfl_xor(d0, 32);
            d1 += __shfl_xor(d1, 16); d1 += __shfl_xor(d1, 32);
            d2 += __shfl_xor(d2, 16); d2 += __shfl_xor(d2, 32);
            d3 += __shfl_xor(d3, 16); d3 += __shfl_xor(d3, 32);
            float sel = d0;
            sel = (g == 1) ? d1 : sel;
            sel = (g == 2) ? d2 : sel;
            sel = (g == 3) ? d3 : sel;
            tk[c] = sel;               // a[b=o4, i=il4+g, c]
        }

        // ---- softmax over c, in registers (|logits| small -> no max-sub) ----
        float s = 0.f;
#pragma unroll
        for (int c = 0; c < CC; ++c) { tk[c] = __expf(tk[c]); s += tk[c]; }
        const float inv = 1.f / s;

        // ---- fold: acc_c += W * (cij .* u), full K over the i-quad ----
#pragma unroll
        for (int c = 0; c < CC; ++c) {
            const float cw = tk[c] * inv;
            const short8v w8 = *(const short8v*)
                &Wb[((size_t)(i0 + il4 + g) * CC + c) * 128 + o4 * 8];
            const short8v bfB = pack8(cw*uf[0], cw*uf[1], cw*uf[2], cw*uf[3],
                                      cw*uf[4], cw*uf[5], cw*uf[6], cw*uf[7]);
            acc[c] = __builtin_amdgcn_mfma_f32_16x16x32_bf16(w8, bfB, acc[c], 0, 0, 0);
        }
    }

    // ---- write partials: seg = 2*blockIdx.x + ih ----
    float* pp = p + (size_t)(blockIdx.x * 2 + ih) * (BB * COW) + (size_t)b_abs * COW;
#pragma unroll
    for (int c = 0; c < CC; ++c)
        *(float4*)(pp + c * DOUT + 4 * g) =
            make_float4(acc[c][0], acc[c][1], acc[c][2], acc[c][3]);
}

// one wave per (b,c): sum partials over nsplit segs, squash, write vout
__global__ __launch_bounds__(64)
void reduce_squash(const float* __restrict__ p, int nsplit, float* __restrict__ vout)
{
    const int bc = blockIdx.x;
    const int b = bc / CC, c = bc % CC;
    const int l = threadIdx.x;
    const int o = l & 15, g = l >> 4;
    const float* base = p + (size_t)b * COW + c * DOUT + o;

    float s = 0.f;
    for (int sp = g; sp < nsplit; sp += 4)
        s += base[(size_t)sp * (BB * COW)];
    s += __shfl_xor(s, 16);
    s += __shfl_xor(s, 32);
    float sq = s * s;
    sq += __shfl_xor(sq, 1);
    sq += __shfl_xor(sq, 2);
    sq += __shfl_xor(sq, 4);
    sq += __shfl_xor(sq, 8);
    const float scale = (sq / (1.f + sq)) * rsqrtf(sq + 1e-9f);
    if (l < 16) vout[b * COW + c * DOUT + o] = s * scale;
}

template<int RLEN>
static void launch_all(const float* u, const float* W, float* out,
                       float* v0, float* v1, ushort* Wb, float* p,
                       hipStream_t stream)
{
    constexpr int NS   = II / RLEN;      // route blocks in i
    constexpr int PSEG = 2 * NS;         // p segments (route: 2 per block)
    constexpr int P0LEN = RLEN / 2;      // pass0 tile (same seg count)

    wcvt<<<WELEMS / (256 * 8), 256, 0, stream>>>(W, Wb);
    caps_pass0_mfma<P0LEN><<<dim3(PSEG, 4), 256, 0, stream>>>(u, Wb, p);
    reduce_squash<<<BB * CC, 64, 0, stream>>>(p, PSEG, v0);
    caps_route<1, RLEN><<<dim3(NS, 4), 512, 0, stream>>>(u, Wb, v0, v0, p);
    reduce_squash<<<BB * CC, 64, 0, stream>>>(p, PSEG, v1);
    caps_route<2, RLEN><<<dim3(NS, 4), 512, 0, stream>>>(u, Wb, v0, v1, p);
    reduce_squash<<<BB * CC, 64, 0, stream>>>(p, PSEG, out);
}

extern "C" void kernel_launch(void* const* d_in, const int* in_sizes, int n_in,
                              void* d_out, int out_size, void* d_ws, size_t ws_size,
                              hipStream_t stream)
{
    const float* u = (const float*)d_in[0];   // [256,2048,8]
    const float* W = (const float*)d_in[1];   // [2048,10,16,8]
    float* out = (float*)d_out;               // [256,10,16]

    const size_t SEG = (size_t)BB * COW;      // 40960 floats
    float*  v0 = (float*)d_ws;
    float*  v1 = v0 + SEG;
    ushort* Wb = (ushort*)(v1 + SEG);         // 32*SEG floats worth
    float*  p  = (float*)(Wb + WELEMS);

    const size_t avail_f = ws_size / sizeof(float);
    // RLEN=32 -> p segs 128 -> need (2+32+128)*SEG floats = ~26.6 MB
    if ((size_t)(34 + 128) * SEG <= avail_f)
        launch_all<32>(u, W, out, v0, v1, Wb, p, stream);
    else
        launch_all<64>(u, W, out, v0, v1, Wb, p, stream);
}

// Round 10
// 97.480 us; speedup vs baseline: 1.8734x; 1.8734x over previous
//
#include <hip/hip_runtime.h>
#include <math.h>

#define BB 256
#define II 2048
#define CC 10
#define DOUT 16
#define COW 160                 // C*DOUT
#define WELEMS (II*CC*DOUT*8)   // 2,621,440 W elements
#define BT 16                   // b per block
#define LEN 32                  // i per block
#define IW 8                    // i per wave
#define NSPLIT (II/LEN)         // 64 p-segments

typedef short  short8v __attribute__((ext_vector_type(8)));
typedef float  f32x4   __attribute__((ext_vector_type(4)));

__device__ __forceinline__ ushort f2bf(float x) {   // RNE f32 -> bf16 bits
    union { float f; unsigned u; } v; v.f = x;
    unsigned r = v.u + 0x7fff + ((v.u >> 16) & 1);
    return (ushort)(r >> 16);
}
__device__ __forceinline__ float bf2f(ushort h) {
    union { unsigned u; float f; } v; v.u = ((unsigned)h) << 16; return v.f;
}
__device__ __forceinline__ short8v pack8(float a0, float a1, float a2, float a3,
                                         float b0, float b1, float b2, float b3) {
    short8v r;
    r[0]=(short)f2bf(a0); r[1]=(short)f2bf(a1); r[2]=(short)f2bf(a2); r[3]=(short)f2bf(a3);
    r[4]=(short)f2bf(b0); r[5]=(short)f2bf(b1); r[6]=(short)f2bf(b2); r[7]=(short)f2bf(b3);
    return r;
}

// ---------------- W f32 -> bf16, once ----------------
__global__ __launch_bounds__(256)
void wcvt(const float* __restrict__ W, ushort* __restrict__ Wb)
{
    const size_t e = ((size_t)blockIdx.x * 256 + threadIdx.x) * 8;
    const float4 x0 = *(const float4*)(W + e);
    const float4 x1 = *(const float4*)(W + e + 4);
    *(short8v*)(Wb + e) = pack8(x0.x, x0.y, x0.z, x0.w, x1.x, x1.y, x1.z, x1.w);
}

// ---------------- unified pass kernel ----------------
// Block: 16 b x 32 i; wave w owns i in [i0+w*8, i0+w*8+8) (2 i-quads).
// Inner loop = round-8-validated masked-MFMA routing pipeline.
// MODE 0: no routing (c_ij uniform; 0.1 applied in squash), B-operand = u8.
// MODE 1: a = uh.v0.  MODE 2: a = uh.(v0+v1).
// Epilogue: cross-wave LDS reduction -> ONE p segment per i-split (blockIdx.x).
template<int MODE>
__global__ __launch_bounds__(256, 3)
void caps_route(const float* __restrict__ u, const ushort* __restrict__ Wb,
                const float* __restrict__ v0, const float* __restrict__ v1,
                float* __restrict__ p)
{
    __shared__ union {
        ushort us[BT * LEN * 8];                // 8 KB  (u tile, bf16)
        float  red[4 * CC * 4 * BT * 4];        // 40 KB [w][c][g][bl][r]
    } sm;

    const int tid = threadIdx.x;
    const int l   = tid & 63;
    const int w   = tid >> 6;        // wave id = i-subrange owner
    const int bl  = l & 15;          // b within tile (B/D col); also A-row o
    const int g   = l >> 4;          // k-group
    const int bbase = blockIdx.y * BT;
    const int b_abs = bbase + bl;
    const int i0    = blockIdx.x * LEN;

    // ---- stage u -> bf16 LDS (coalesced: 64 lanes cover 1KB of one b) ----
    for (int e = tid; e < BT * LEN * 2; e += 256) {
        const int rb = e >> 6, rem = e & 63;
        const int i = rem >> 1, dh = (rem & 1) * 4;
        const float4 x = *(const float4*)(u + ((size_t)(bbase + rb) * II + i0 + i) * 8 + dh);
        ushort4 h;
        h.x = f2bf(x.x); h.y = f2bf(x.y); h.z = f2bf(x.z); h.w = f2bf(x.w);
        *(ushort4*)&sm.us[(rb * LEN + (i ^ (rb & 7))) * 8 + dh] = h;
    }

    // ---- v (or v0+v1) regs: vreg[c][r] = v[b, c, o=4g+r] ----
    float vreg[CC][4];
    if constexpr (MODE >= 1) {
#pragma unroll
        for (int c = 0; c < CC; ++c) {
            float4 x = *(const float4*)(v0 + b_abs * COW + c * DOUT + 4 * g);
            if constexpr (MODE == 2) {
                const float4 y = *(const float4*)(v1 + b_abs * COW + c * DOUT + 4 * g);
                x.x += y.x; x.y += y.y; x.z += y.z; x.w += y.w;
            }
            vreg[c][0] = x.x; vreg[c][1] = x.y; vreg[c][2] = x.z; vreg[c][3] = x.w;
        }
    }

    f32x4 acc[CC];
#pragma unroll
    for (int c = 0; c < CC; ++c) acc[c] = (f32x4){0.f, 0.f, 0.f, 0.f};
    const short8v zero8 = {0,0,0,0,0,0,0,0};
    const f32x4   zacc  = (f32x4){0.f, 0.f, 0.f, 0.f};

    __syncthreads();

#pragma unroll
    for (int iq = 0; iq < IW / 4; ++iq) {
        const int ig   = i0 + w * IW + iq * 4;   // global i base of this quad
        const int iloc = w * IW + iq * 4;        // block-local
        const short8v u8 = *(const short8v*)
            &sm.us[(bl * LEN + ((iloc + g) ^ (bl & 7))) * 8];

        if constexpr (MODE == 0) {
            // ---- dense fold only: acc_c += W * u over the i-quad ----
#pragma unroll
            for (int c = 0; c < CC; ++c) {
                const short8v w8 = *(const short8v*)
                    &Wb[((size_t)(ig + g) * CC + c) * 128 + bl * 8];
                acc[c] = __builtin_amdgcn_mfma_f32_16x16x32_bf16(w8, u8, acc[c], 0, 0, 0);
            }
        } else {
            float uf[8];
#pragma unroll
            for (int e = 0; e < 8; ++e) uf[e] = bf2f((ushort)u8[e]);

            float tk[CC];
            // ---- agreement (round-8-validated) ----
#pragma unroll
            for (int c = 0; c < CC; ++c) {
                const short8v w8 = *(const short8v*)
                    &Wb[((size_t)(ig + g) * CC + c) * 128 + bl * 8];
                f32x4 uh[4];
#pragma unroll
                for (int j = 0; j < 4; ++j)
                    uh[j] = __builtin_amdgcn_mfma_f32_16x16x32_bf16(
                        w8, (g == j) ? u8 : zero8, zacc, 0, 0, 0);
                float d0 = uh[0][0]*vreg[c][0] + uh[0][1]*vreg[c][1]
                         + uh[0][2]*vreg[c][2] + uh[0][3]*vreg[c][3];
                float d1 = uh[1][0]*vreg[c][0] + uh[1][1]*vreg[c][1]
                         + uh[1][2]*vreg[c][2] + uh[1][3]*vreg[c][3];
                float d2 = uh[2][0]*vreg[c][0] + uh[2][1]*vreg[c][1]
                         + uh[2][2]*vreg[c][2] + uh[2][3]*vreg[c][3];
                float d3 = uh[3][0]*vreg[c][0] + uh[3][1]*vreg[c][1]
                         + uh[3][2]*vreg[c][2] + uh[3][3]*vreg[c][3];
                d0 += __shfl_xor(d0, 16); d0 += __shfl_xor(d0, 32);
                d1 += __shfl_xor(d1, 16); d1 += __shfl_xor(d1, 32);
                d2 += __shfl_xor(d2, 16); d2 += __shfl_xor(d2, 32);
                d3 += __shfl_xor(d3, 16); d3 += __shfl_xor(d3, 32);
                float sel = d0;
                sel = (g == 1) ? d1 : sel;
                sel = (g == 2) ? d2 : sel;
                sel = (g == 3) ? d3 : sel;
                tk[c] = sel;               // a[b=bl, i=ig+g, c]
            }

            // ---- softmax over c in regs (|logits| small -> no max-sub) ----
            float s = 0.f;
#pragma unroll
            for (int c = 0; c < CC; ++c) { tk[c] = __expf(tk[c]); s += tk[c]; }
            const float inv = 1.f / s;

            // ---- fold: acc_c += W * (cij .* u), full K over the i-quad ----
#pragma unroll
            for (int c = 0; c < CC; ++c) {
                const float cw = tk[c] * inv;
                const short8v w8 = *(const short8v*)
                    &Wb[((size_t)(ig + g) * CC + c) * 128 + bl * 8];
                const short8v bfB = pack8(cw*uf[0], cw*uf[1], cw*uf[2], cw*uf[3],
                                          cw*uf[4], cw*uf[5], cw*uf[6], cw*uf[7]);
                acc[c] = __builtin_amdgcn_mfma_f32_16x16x32_bf16(w8, bfB, acc[c], 0, 0, 0);
            }
        }
    }

    // ---- cross-wave reduction: 4 waves -> one p segment per block ----
    __syncthreads();                       // all waves done with sm.us
#pragma unroll
    for (int c = 0; c < CC; ++c)
        *(f32x4*)&sm.red[(((w * CC + c) * 4 + g) * BT + bl) * 4] = acc[c];
    __syncthreads();

    float* pp = p + (size_t)blockIdx.x * (BB * COW) + (size_t)b_abs * COW;
    for (int c = w * 3; c < CC && c < w * 3 + 3; ++c) {   // w0:0-2 w1:3-5 w2:6-8 w3:9
        f32x4 sacc = (f32x4){0.f, 0.f, 0.f, 0.f};
#pragma unroll
        for (int ww = 0; ww < 4; ++ww) {
            const f32x4 t = *(const f32x4*)&sm.red[(((ww * CC + c) * 4 + g) * BT + bl) * 4];
            sacc[0] += t[0]; sacc[1] += t[1]; sacc[2] += t[2]; sacc[3] += t[3];
        }
        *(float4*)(pp + c * DOUT + 4 * g) =
            make_float4(sacc[0], sacc[1], sacc[2], sacc[3]);
    }
}

// one wave per (b,c): sum partials over nsplit segs (2 ILP chains), scale,
// squash, write vout
__global__ __launch_bounds__(64)
void reduce_squash(const float* __restrict__ p, int nsplit, float scale,
                   float* __restrict__ vout)
{
    const int bc = blockIdx.x;
    const int b = bc / CC, c = bc % CC;
    const int l = threadIdx.x;
    const int o = l & 15, g = l >> 4;
    const float* base = p + (size_t)b * COW + c * DOUT + o;

    float s0 = 0.f, s1 = 0.f;
    for (int sp = g; sp < nsplit; sp += 8)
        s0 += base[(size_t)sp * (BB * COW)];
    for (int sp = g + 4; sp < nsplit; sp += 8)
        s1 += base[(size_t)sp * (BB * COW)];
    float s = s0 + s1;
    s += __shfl_xor(s, 16);
    s += __shfl_xor(s, 32);
    s *= scale;
    float sq = s * s;
    sq += __shfl_xor(sq, 1);
    sq += __shfl_xor(sq, 2);
    sq += __shfl_xor(sq, 4);
    sq += __shfl_xor(sq, 8);
    const float sc = (sq / (1.f + sq)) * rsqrtf(sq + 1e-9f);
    if (l < 16) vout[b * COW + c * DOUT + o] = s * sc;
}

extern "C" void kernel_launch(void* const* d_in, const int* in_sizes, int n_in,
                              void* d_out, int out_size, void* d_ws, size_t ws_size,
                              hipStream_t stream)
{
    const float* u = (const float*)d_in[0];   // [256,2048,8]
    const float* W = (const float*)d_in[1];   // [2048,10,16,8]
    float* out = (float*)d_out;               // [256,10,16]

    const size_t SEG = (size_t)BB * COW;      // 40960 floats
    float*  v0 = (float*)d_ws;
    float*  v1 = v0 + SEG;
    ushort* Wb = (ushort*)(v1 + SEG);         // 5.25 MB
    float*  p  = (float*)(Wb + WELEMS);       // NSPLIT * 160KB = 10.5 MB

    dim3 grid(NSPLIT, BB / BT);               // (64, 16) = 1024 blocks

    wcvt<<<WELEMS / (256 * 8), 256, 0, stream>>>(W, Wb);
    caps_route<0><<<grid, 256, 0, stream>>>(u, Wb, nullptr, nullptr, p);
    reduce_squash<<<BB * CC, 64, 0, stream>>>(p, NSPLIT, 0.1f, v0);
    caps_route<1><<<grid, 256, 0, stream>>>(u, Wb, v0, v0, p);
    reduce_squash<<<BB * CC, 64, 0, stream>>>(p, NSPLIT, 1.f, v1);
    caps_route<2><<<grid, 256, 0, stream>>>(u, Wb, v0, v1, p);
    reduce_squash<<<BB * CC, 64, 0, stream>>>(p, NSPLIT, 1.f, out);
}

// Round 11
// 93.833 us; speedup vs baseline: 1.9462x; 1.0389x over previous
//
#include <hip/hip_runtime.h>
#include <math.h>

#define BB 256
#define II 2048
#define CC 10
#define DOUT 16
#define COW 160                 // C*DOUT
#define WELEMS (II*CC*DOUT*8)   // 2,621,440 W elements
#define BT 16                   // b per block
#define LEN 64                  // i per block
#define IW 16                   // i per wave (4 i-quads)
#define NSPLIT (II/LEN)         // 32 p-segments

typedef short  short8v __attribute__((ext_vector_type(8)));
typedef float  f32x4   __attribute__((ext_vector_type(4)));

__device__ __forceinline__ ushort f2bf(float x) {   // RNE f32 -> bf16 bits
    union { float f; unsigned u; } v; v.f = x;
    unsigned r = v.u + 0x7fff + ((v.u >> 16) & 1);
    return (ushort)(r >> 16);
}
__device__ __forceinline__ float bf2f(ushort h) {
    union { unsigned u; float f; } v; v.u = ((unsigned)h) << 16; return v.f;
}
__device__ __forceinline__ short8v pack8(float a0, float a1, float a2, float a3,
                                         float b0, float b1, float b2, float b3) {
    short8v r;
    r[0]=(short)f2bf(a0); r[1]=(short)f2bf(a1); r[2]=(short)f2bf(a2); r[3]=(short)f2bf(a3);
    r[4]=(short)f2bf(b0); r[5]=(short)f2bf(b1); r[6]=(short)f2bf(b2); r[7]=(short)f2bf(b3);
    return r;
}

// ---------------- W f32 -> bf16, once ----------------
__global__ __launch_bounds__(256)
void wcvt(const float* __restrict__ W, ushort* __restrict__ Wb)
{
    const size_t e = ((size_t)blockIdx.x * 256 + threadIdx.x) * 8;
    const float4 x0 = *(const float4*)(W + e);
    const float4 x1 = *(const float4*)(W + e + 4);
    *(short8v*)(Wb + e) = pack8(x0.x, x0.y, x0.z, x0.w, x1.x, x1.y, x1.z, x1.w);
}

// ---------------- unified pass kernel ----------------
// Block: 16 b x 64 i; wave w owns i in [i0+w*16, i0+w*16+16) (4 i-quads).
// MODE 0: no routing (0.1 applied in squash). MODE 1: a=uh.v0. MODE 2: a=uh.(v0+v1).
// Epilogue: cross-wave LDS reduction -> ONE p segment per i-split.
template<int MODE>
__global__ __launch_bounds__(256, 3)
void caps_route(const float* __restrict__ u, const ushort* __restrict__ Wb,
                const float* __restrict__ v0, const float* __restrict__ v1,
                float* __restrict__ p)
{
    __shared__ union {
        ushort us[BT * LEN * 8];                // 16 KB (u tile, bf16)
        float  red[4 * CC * 4 * BT * 4];        // 40 KB [w][c][g][bl][r]
    } sm;

    const int tid = threadIdx.x;
    const int l   = tid & 63;
    const int w   = tid >> 6;        // wave id = i-subrange owner
    const int bl  = l & 15;          // b within tile (B/D col); also A-row o
    const int g   = l >> 4;          // k-group
    const int bbase = blockIdx.y * BT;
    const int b_abs = bbase + bl;
    const int i0    = blockIdx.x * LEN;

    // ---- stage u -> bf16 LDS (coalesced) ----
    for (int e = tid; e < BT * LEN * 2; e += 256) {
        const int rb = e / (LEN * 2), rem = e % (LEN * 2);
        const int i = rem >> 1, dh = (rem & 1) * 4;
        const float4 x = *(const float4*)(u + ((size_t)(bbase + rb) * II + i0 + i) * 8 + dh);
        ushort4 h;
        h.x = f2bf(x.x); h.y = f2bf(x.y); h.z = f2bf(x.z); h.w = f2bf(x.w);
        *(ushort4*)&sm.us[(rb * LEN + (i ^ (rb & 7))) * 8 + dh] = h;
    }

    // ---- v (or v0+v1) regs: vreg[c][r] = v[b, c, o=4g+r] ----
    float vreg[CC][4];
    if constexpr (MODE >= 1) {
#pragma unroll
        for (int c = 0; c < CC; ++c) {
            float4 x = *(const float4*)(v0 + b_abs * COW + c * DOUT + 4 * g);
            if constexpr (MODE == 2) {
                const float4 y = *(const float4*)(v1 + b_abs * COW + c * DOUT + 4 * g);
                x.x += y.x; x.y += y.y; x.z += y.z; x.w += y.w;
            }
            vreg[c][0] = x.x; vreg[c][1] = x.y; vreg[c][2] = x.z; vreg[c][3] = x.w;
        }
    }

    f32x4 acc[CC];
#pragma unroll
    for (int c = 0; c < CC; ++c) acc[c] = (f32x4){0.f, 0.f, 0.f, 0.f};
    const short8v zero8 = {0,0,0,0,0,0,0,0};
    const f32x4   zacc  = (f32x4){0.f, 0.f, 0.f, 0.f};

    __syncthreads();

#pragma unroll
    for (int iq = 0; iq < IW / 4; ++iq) {
        const int ig   = i0 + w * IW + iq * 4;   // global i base of this quad
        const int iloc = w * IW + iq * 4;        // block-local
        const short8v u8 = *(const short8v*)
            &sm.us[(bl * LEN + ((iloc + g) ^ (bl & 7))) * 8];

        if constexpr (MODE == 0) {
            // ---- dense fold only: acc_c += W * u over the i-quad ----
#pragma unroll
            for (int c = 0; c < CC; ++c) {
                const short8v w8 = *(const short8v*)
                    &Wb[((size_t)(ig + g) * CC + c) * 128 + bl * 8];
                acc[c] = __builtin_amdgcn_mfma_f32_16x16x32_bf16(w8, u8, acc[c], 0, 0, 0);
            }
        } else {
            float uf[8];
#pragma unroll
            for (int e = 0; e < 8; ++e) uf[e] = bf2f((ushort)u8[e]);

            float tk[CC];
            // ---- agreement (round-8-validated) ----
#pragma unroll
            for (int c = 0; c < CC; ++c) {
                const short8v w8 = *(const short8v*)
                    &Wb[((size_t)(ig + g) * CC + c) * 128 + bl * 8];
                f32x4 uh[4];
#pragma unroll
                for (int j = 0; j < 4; ++j)
                    uh[j] = __builtin_amdgcn_mfma_f32_16x16x32_bf16(
                        w8, (g == j) ? u8 : zero8, zacc, 0, 0, 0);
                float d0 = uh[0][0]*vreg[c][0] + uh[0][1]*vreg[c][1]
                         + uh[0][2]*vreg[c][2] + uh[0][3]*vreg[c][3];
                float d1 = uh[1][0]*vreg[c][0] + uh[1][1]*vreg[c][1]
                         + uh[1][2]*vreg[c][2] + uh[1][3]*vreg[c][3];
                float d2 = uh[2][0]*vreg[c][0] + uh[2][1]*vreg[c][1]
                         + uh[2][2]*vreg[c][2] + uh[2][3]*vreg[c][3];
                float d3 = uh[3][0]*vreg[c][0] + uh[3][1]*vreg[c][1]
                         + uh[3][2]*vreg[c][2] + uh[3][3]*vreg[c][3];
                d0 += __shfl_xor(d0, 16); d0 += __shfl_xor(d0, 32);
                d1 += __shfl_xor(d1, 16); d1 += __shfl_xor(d1, 32);
                d2 += __shfl_xor(d2, 16); d2 += __shfl_xor(d2, 32);
                d3 += __shfl_xor(d3, 16); d3 += __shfl_xor(d3, 32);
                float sel = d0;
                sel = (g == 1) ? d1 : sel;
                sel = (g == 2) ? d2 : sel;
                sel = (g == 3) ? d3 : sel;
                tk[c] = sel;               // a[b=bl, i=ig+g, c]
            }

            // ---- softmax over c in regs (|logits| small -> no max-sub) ----
            float s = 0.f;
#pragma unroll
            for (int c = 0; c < CC; ++c) { tk[c] = __expf(tk[c]); s += tk[c]; }
            const float inv = 1.f / s;

            // ---- fold: acc_c += W * (cij .* u), full K over the i-quad ----
#pragma unroll
            for (int c = 0; c < CC; ++c) {
                const float cw = tk[c] * inv;
                const short8v w8 = *(const short8v*)
                    &Wb[((size_t)(ig + g) * CC + c) * 128 + bl * 8];
                const short8v bfB = pack8(cw*uf[0], cw*uf[1], cw*uf[2], cw*uf[3],
                                          cw*uf[4], cw*uf[5], cw*uf[6], cw*uf[7]);
                acc[c] = __builtin_amdgcn_mfma_f32_16x16x32_bf16(w8, bfB, acc[c], 0, 0, 0);
            }
        }
    }

    // ---- cross-wave reduction: 4 waves -> one p segment per block ----
    __syncthreads();                       // all waves done with sm.us
#pragma unroll
    for (int c = 0; c < CC; ++c)
        *(f32x4*)&sm.red[(((w * CC + c) * 4 + g) * BT + bl) * 4] = acc[c];
    __syncthreads();

    float* pp = p + (size_t)blockIdx.x * (BB * COW) + (size_t)b_abs * COW;
    for (int c = w * 3; c < CC && c < w * 3 + 3; ++c) {   // w0:0-2 w1:3-5 w2:6-8 w3:9
        f32x4 sacc = (f32x4){0.f, 0.f, 0.f, 0.f};
#pragma unroll
        for (int ww = 0; ww < 4; ++ww) {
            const f32x4 t = *(const f32x4*)&sm.red[(((ww * CC + c) * 4 + g) * BT + bl) * 4];
            sacc[0] += t[0]; sacc[1] += t[1]; sacc[2] += t[2]; sacc[3] += t[3];
        }
        *(float4*)(pp + c * DOUT + 4 * g) =
            make_float4(sacc[0], sacc[1], sacc[2], sacc[3]);
    }
}

// one wave per (b,c): sum partials over nsplit segs (2 ILP chains), scale,
// squash, write vout
__global__ __launch_bounds__(64)
void reduce_squash(const float* __restrict__ p, int nsplit, float scale,
                   float* __restrict__ vout)
{
    const int bc = blockIdx.x;
    const int b = bc / CC, c = bc % CC;
    const int l = threadIdx.x;
    const int o = l & 15, g = l >> 4;
    const float* base = p + (size_t)b * COW + c * DOUT + o;

    float s0 = 0.f, s1 = 0.f;
    for (int sp = g; sp < nsplit; sp += 8)
        s0 += base[(size_t)sp * (BB * COW)];
    for (int sp = g + 4; sp < nsplit; sp += 8)
        s1 += base[(size_t)sp * (BB * COW)];
    float s = s0 + s1;
    s += __shfl_xor(s, 16);
    s += __shfl_xor(s, 32);
    s *= scale;
    float sq = s * s;
    sq += __shfl_xor(sq, 1);
    sq += __shfl_xor(sq, 2);
    sq += __shfl_xor(sq, 4);
    sq += __shfl_xor(sq, 8);
    const float sc = (sq / (1.f + sq)) * rsqrtf(sq + 1e-9f);
    if (l < 16) vout[b * COW + c * DOUT + o] = s * sc;
}

extern "C" void kernel_launch(void* const* d_in, const int* in_sizes, int n_in,
                              void* d_out, int out_size, void* d_ws, size_t ws_size,
                              hipStream_t stream)
{
    const float* u = (const float*)d_in[0];   // [256,2048,8]
    const float* W = (const float*)d_in[1];   // [2048,10,16,8]
    float* out = (float*)d_out;               // [256,10,16]

    const size_t SEG = (size_t)BB * COW;      // 40960 floats
    float*  v0 = (float*)d_ws;
    float*  v1 = v0 + SEG;
    ushort* Wb = (ushort*)(v1 + SEG);         // 5.25 MB
    float*  p  = (float*)(Wb + WELEMS);       // NSPLIT * 160KB = 5.25 MB

    dim3 grid(NSPLIT, BB / BT);               // (32, 16) = 512 blocks

    wcvt<<<WELEMS / (256 * 8), 256, 0, stream>>>(W, Wb);
    caps_route<0><<<grid, 256, 0, stream>>>(u, Wb, nullptr, nullptr, p);
    reduce_squash<<<BB * CC, 64, 0, stream>>>(p, NSPLIT, 0.1f, v0);
    caps_route<1><<<grid, 256, 0, stream>>>(u, Wb, v0, v0, p);
    reduce_squash<<<BB * CC, 64, 0, stream>>>(p, NSPLIT, 1.f, v1);
    caps_route<2><<<grid, 256, 0, stream>>>(u, Wb, v0, v1, p);
    reduce_squash<<<BB * CC, 64, 0, stream>>>(p, NSPLIT, 1.f, out);
}